// Round 2
// baseline (677.084 us; speedup 1.0000x reference)
//
#include <hip/hip_runtime.h>

#define N_DRUG 572
#define DIM 512
#define KNBR 64
#define MAXDEG 32

// C[M x 512] = A[M x Kdim] @ B[Kdim x 512]; A is gathered/mixed per mode.
// mode 0: A = drugW[drug_name[r]][k]            (Kdim=512), no epilogue
// mode 1: A = k<512 ? agg[r][k] : drugW[drug_name[r]][k-512] (Kdim=1024),
//         epilogue: +bias, ReLU
__global__ __launch_bounds__(256) void gemm_kernel(
    const float* __restrict__ drugW, const int* __restrict__ drug_name,
    const float* __restrict__ agg, const float* __restrict__ B,
    const float* __restrict__ bias, float* __restrict__ C,
    int M, int Kdim, int mode)
{
    __shared__ float As[32][64];   // transposed: As[k][m]
    __shared__ float Bs[32][64];   // Bs[k][c]
    const int t = threadIdx.x;
    const int c0 = blockIdx.x * 64;
    const int r0 = blockIdx.y * 64;
    const int tn = t & 15, tm = t >> 4;
    const int am = t & 63, ak0 = (t >> 6) * 8;
    const int bk = t >> 3, bc = (t & 7) * 8;
    const int arow = r0 + am;

    float acc[4][4] = {{0.f}};

    for (int ks = 0; ks < Kdim; ks += 32) {
        float av[8], bv[8];
        if (arow < M) {
            const int k = ks + ak0;
            const float* src;
            if (mode == 1 && k < 512) {
                src = agg + (size_t)arow * 512 + k;
            } else {
                const int kk2 = (mode == 1) ? (k - 512) : k;
                src = drugW + (size_t)drug_name[arow] * 512 + kk2;
            }
            const float4 x = ((const float4*)src)[0];
            const float4 y = ((const float4*)src)[1];
            av[0]=x.x; av[1]=x.y; av[2]=x.z; av[3]=x.w;
            av[4]=y.x; av[5]=y.y; av[6]=y.z; av[7]=y.w;
        } else {
            #pragma unroll
            for (int j = 0; j < 8; ++j) av[j] = 0.f;
        }
        {
            const float* src = B + (size_t)(ks + bk) * 512 + c0 + bc;
            const float4 x = ((const float4*)src)[0];
            const float4 y = ((const float4*)src)[1];
            bv[0]=x.x; bv[1]=x.y; bv[2]=x.z; bv[3]=x.w;
            bv[4]=y.x; bv[5]=y.y; bv[6]=y.z; bv[7]=y.w;
        }

        __syncthreads();
        #pragma unroll
        for (int j = 0; j < 8; ++j) As[ak0 + j][am] = av[j];
        #pragma unroll
        for (int j = 0; j < 8; ++j) Bs[bk][bc + j] = bv[j];
        __syncthreads();

        #pragma unroll
        for (int kk = 0; kk < 32; ++kk) {
            const float4 a = *(const float4*)&As[kk][tm * 4];
            const float4 b = *(const float4*)&Bs[kk][tn * 4];
            const float ar[4] = {a.x, a.y, a.z, a.w};
            const float br[4] = {b.x, b.y, b.z, b.w};
            #pragma unroll
            for (int i = 0; i < 4; ++i)
                #pragma unroll
                for (int j = 0; j < 4; ++j)
                    acc[i][j] = fmaf(ar[i], br[j], acc[i][j]);
        }
    }
    #pragma unroll
    for (int i = 0; i < 4; ++i) {
        const int r = r0 + tm * 4 + i;
        if (r >= M) continue;
        #pragma unroll
        for (int j = 0; j < 4; ++j) {
            const int cc = c0 + tn * 4 + j;
            float v = acc[i][j];
            if (mode == 1) {
                v += bias[cc];
                v = fmaxf(v, 0.f);
            }
            C[(size_t)r * 512 + cc] = v;
        }
    }
}

// one block per drug n: scores = (q[n] . rela[adj_rel[n,k]]) / sqrt(512),
// softmax over k, agg[n] = sum_k attn_k * ent[adj_tail[n,k]]
__global__ __launch_bounds__(256) void attn_kernel(
    const float* __restrict__ relaW, const float* __restrict__ entW,
    const int* __restrict__ adj_tail, const int* __restrict__ adj_rel,
    const float* __restrict__ q, float* __restrict__ agg)
{
    const int n = blockIdx.x;
    const int t = threadIdx.x;
    const int lane = t & 63;
    const int w = t >> 6;
    __shared__ float sc[64];
    __shared__ int tails[64];
    __shared__ int rels[64];
    if (t < 64) { tails[t] = adj_tail[n * 64 + t]; rels[t] = adj_rel[n * 64 + t]; }

    float qv[8];
    {
        const float4* p = (const float4*)(q + (size_t)n * 512 + lane * 8);
        float4 x = p[0], y = p[1];
        qv[0]=x.x; qv[1]=x.y; qv[2]=x.z; qv[3]=x.w;
        qv[4]=y.x; qv[5]=y.y; qv[6]=y.z; qv[7]=y.w;
    }
    __syncthreads();

    // each of the 4 waves computes 16 scores; each score is a 64-lane dot
    #pragma unroll 4
    for (int kk = 0; kk < 16; ++kk) {
        const int k = w * 16 + kk;
        const float4* p = (const float4*)(relaW + (size_t)rels[k] * 512 + lane * 8);
        float4 x = p[0], y = p[1];
        float s = 0.f;
        s = fmaf(qv[0], x.x, s); s = fmaf(qv[1], x.y, s);
        s = fmaf(qv[2], x.z, s); s = fmaf(qv[3], x.w, s);
        s = fmaf(qv[4], y.x, s); s = fmaf(qv[5], y.y, s);
        s = fmaf(qv[6], y.z, s); s = fmaf(qv[7], y.w, s);
        #pragma unroll
        for (int off = 32; off >= 1; off >>= 1) s += __shfl_xor(s, off, 64);
        if (lane == 0) sc[k] = s * 0.0441941738241592f;  // 1/sqrt(512)
    }
    __syncthreads();

    if (w == 0) {
        float s = sc[lane];
        float m = s;
        #pragma unroll
        for (int off = 32; off >= 1; off >>= 1) m = fmaxf(m, __shfl_xor(m, off, 64));
        const float e = __expf(s - m);
        float sum = e;
        #pragma unroll
        for (int off = 32; off >= 1; off >>= 1) sum += __shfl_xor(sum, off, 64);
        sc[lane] = e / sum;
    }
    __syncthreads();

    // agg: thread t covers columns 2t, 2t+1
    float a0 = 0.f, a1 = 0.f;
    const int d2 = t * 2;
    #pragma unroll 8
    for (int k = 0; k < 64; ++k) {
        const float ak = sc[k];
        const float2 u = *(const float2*)(entW + (size_t)tails[k] * 512 + d2);
        a0 = fmaf(ak, u.x, a0);
        a1 = fmaf(ak, u.y, a1);
    }
    ((float2*)(agg + (size_t)n * 512))[t] = make_float2(a0, a1);
}

// per-column mean/var over 572 rows -> fused scale/shift for BN
__global__ __launch_bounds__(256) void bn_stats_kernel(
    const float* __restrict__ h, const float* __restrict__ gamma,
    const float* __restrict__ beta, float* __restrict__ scale,
    float* __restrict__ shift)
{
    const int t = threadIdx.x;
    const int c = blockIdx.x * 64 + (t & 63);
    const int g = t >> 6;
    float s = 0.f, sq = 0.f;
    for (int r = g; r < N_DRUG; r += 4) {
        const float v = h[(size_t)r * 512 + c];
        s += v;
        sq = fmaf(v, v, sq);
    }
    __shared__ float S[4][64], Q[4][64];
    S[g][t & 63] = s; Q[g][t & 63] = sq;
    __syncthreads();
    if (t < 64) {
        const int cc = blockIdx.x * 64 + t;
        s  = S[0][t] + S[1][t] + S[2][t] + S[3][t];
        sq = Q[0][t] + Q[1][t] + Q[2][t] + Q[3][t];
        const float mean = s * (1.f / N_DRUG);
        const float var = sq * (1.f / N_DRUG) - mean * mean;
        const float rstd = rsqrtf(var + 1e-5f);
        const float ga = gamma[cc];
        scale[cc] = ga * rstd;
        shift[cc] = beta[cc] - mean * ga * rstd;
    }
}

// sequential smoothing scan; columns are independent -> 32 blocks x 16 cols.
// single wave per block; f-slice lives in LDS; 4 lanes per column split the
// neighbor sum; neighbor indices live in registers (lanes 0..31) and are
// broadcast with __shfl so the LDS critical path is only the fs reads.
// hout is BOTH the input h (read fully first) and the final output buffer.
__global__ __launch_bounds__(64) void scan_kernel(
    float* hout, const float* __restrict__ scale,
    const float* __restrict__ shift, const int* __restrict__ nbr_idx,
    const int* __restrict__ nbr_deg, const int* __restrict__ epoch,
    int dummy)
{
    __shared__ float fs[N_DRUG * 16];
    __shared__ int degs[N_DRUG];
    const int t = threadIdx.x;
    const int c = t & 15;
    const int j4 = t >> 4;
    const int c0 = blockIdx.x * 16;
    const float scl = scale[c0 + c];
    const float shf = shift[c0 + c];
    for (int r = j4; r < N_DRUG; r += 4)
        fs[r * 16 + c] = fmaf(hout[(size_t)r * 512 + c0 + c], scl, shf);
    for (int i = t; i < N_DRUG; i += 64) degs[i] = nbr_deg[i];
    __syncthreads();

    if (epoch[0] > 1) {
        int cur = (t < 32) ? nbr_idx[t] : 0;
        for (int i = 0; i < N_DRUG; ++i) {
            int nxt = 0;
            if (t < 32 && i + 1 < N_DRUG) nxt = nbr_idx[(i + 1) * 32 + t];
            const int deg = degs[i];          // uniform across wave
            const float curf = fs[i * 16 + c];
            float newv = curf;
            if (deg > 0) {
                float s = 0.f;
                #pragma unroll
                for (int u = 0; u < 8; ++u) {
                    const int m = j4 + u * 4;
                    const int pos = __shfl(cur, m, 64);
                    if (m < deg) s += fs[pos * 16 + c];
                }
                s += __shfl_xor(s, 16, 64);
                s += __shfl_xor(s, 32, 64);
                newv = (s / (float)deg + curf) * 0.5f;
            }
            if (t < 16) fs[i * 16 + c] = newv;
            cur = nxt;
            __syncthreads();   // single wave: cheap; pins DS order
        }
    }
    __syncthreads();
    for (int r = j4; r < N_DRUG; r += 4)
        hout[(size_t)r * 512 + c0 + c] = fs[r * 16 + c];
}

extern "C" void kernel_launch(void* const* d_in, const int* in_sizes, int n_in,
                              void* d_out, int out_size, void* d_ws, size_t ws_size,
                              hipStream_t stream)
{
    const float* drugW = (const float*)d_in[0];
    const float* relaW = (const float*)d_in[1];
    const float* entW  = (const float*)d_in[2];
    const float* Wa    = (const float*)d_in[3];
    const float* linW  = (const float*)d_in[4];
    const float* linb  = (const float*)d_in[5];
    const float* gamma = (const float*)d_in[6];
    const float* beta  = (const float*)d_in[7];
    const int* drug_name = (const int*)d_in[8];
    const int* adj_tail  = (const int*)d_in[9];
    const int* adj_rel   = (const int*)d_in[10];
    const int* nbr_idx   = (const int*)d_in[11];
    const int* nbr_deg   = (const int*)d_in[12];
    const int* epoch     = (const int*)d_in[13];

    float* ws = (float*)d_ws;
    float* q     = ws;                              // [572,512]
    float* agg   = ws + (size_t)N_DRUG * 512;       // [572,512]
    float* scale = ws + (size_t)2 * N_DRUG * 512;   // [512]
    float* shift = scale + 512;                     // [512]
    float* h = (float*)d_out;                       // h lives in d_out, overwritten in-place by scan

    dim3 ggrid(8, 9);
    gemm_kernel<<<ggrid, 256, 0, stream>>>(drugW, drug_name, nullptr, Wa, nullptr, q,
                                           N_DRUG, 512, 0);
    attn_kernel<<<N_DRUG, 256, 0, stream>>>(relaW, entW, adj_tail, adj_rel, q, agg);
    gemm_kernel<<<ggrid, 256, 0, stream>>>(drugW, drug_name, agg, linW, linb, h,
                                           N_DRUG, 1024, 1);
    bn_stats_kernel<<<8, 256, 0, stream>>>(h, gamma, beta, scale, shift);
    scan_kernel<<<32, 64, 0, stream>>>(h, scale, shift, nbr_idx, nbr_deg, epoch, 0);
}

// Round 3
// 377.982 us; speedup vs baseline: 1.7913x; 1.7913x over previous
//
#include <hip/hip_runtime.h>

#define N_DRUG 572
#define DIM 512
#define KNBR 64
#define MAXDEG 32
#define FS_STRIDE 17   // 16 cols + 1 pad -> conflict-free LDS rows

// C[M x 512] = A[M x Kdim] @ B[Kdim x 512]; A is gathered/mixed per mode.
// mode 0: A = drugW[drug_name[r]][k]            (Kdim=512), no epilogue
// mode 1: A = k<512 ? agg[r][k] : drugW[drug_name[r]][k-512] (Kdim=1024),
//         epilogue: +bias, ReLU
__global__ __launch_bounds__(256) void gemm_kernel(
    const float* __restrict__ drugW, const int* __restrict__ drug_name,
    const float* __restrict__ agg, const float* __restrict__ B,
    const float* __restrict__ bias, float* __restrict__ C,
    int M, int Kdim, int mode)
{
    __shared__ float As[32][64];   // transposed: As[k][m]
    __shared__ float Bs[32][64];   // Bs[k][c]
    const int t = threadIdx.x;
    const int c0 = blockIdx.x * 64;
    const int r0 = blockIdx.y * 64;
    const int tn = t & 15, tm = t >> 4;
    const int am = t & 63, ak0 = (t >> 6) * 8;
    const int bk = t >> 3, bc = (t & 7) * 8;
    const int arow = r0 + am;

    float acc[4][4] = {{0.f}};

    for (int ks = 0; ks < Kdim; ks += 32) {
        float av[8], bv[8];
        if (arow < M) {
            const int k = ks + ak0;
            const float* src;
            if (mode == 1 && k < 512) {
                src = agg + (size_t)arow * 512 + k;
            } else {
                const int kk2 = (mode == 1) ? (k - 512) : k;
                src = drugW + (size_t)drug_name[arow] * 512 + kk2;
            }
            const float4 x = ((const float4*)src)[0];
            const float4 y = ((const float4*)src)[1];
            av[0]=x.x; av[1]=x.y; av[2]=x.z; av[3]=x.w;
            av[4]=y.x; av[5]=y.y; av[6]=y.z; av[7]=y.w;
        } else {
            #pragma unroll
            for (int j = 0; j < 8; ++j) av[j] = 0.f;
        }
        {
            const float* src = B + (size_t)(ks + bk) * 512 + c0 + bc;
            const float4 x = ((const float4*)src)[0];
            const float4 y = ((const float4*)src)[1];
            bv[0]=x.x; bv[1]=x.y; bv[2]=x.z; bv[3]=x.w;
            bv[4]=y.x; bv[5]=y.y; bv[6]=y.z; bv[7]=y.w;
        }

        __syncthreads();
        #pragma unroll
        for (int j = 0; j < 8; ++j) As[ak0 + j][am] = av[j];
        #pragma unroll
        for (int j = 0; j < 8; ++j) Bs[bk][bc + j] = bv[j];
        __syncthreads();

        #pragma unroll
        for (int kk = 0; kk < 32; ++kk) {
            const float4 a = *(const float4*)&As[kk][tm * 4];
            const float4 b = *(const float4*)&Bs[kk][tn * 4];
            const float ar[4] = {a.x, a.y, a.z, a.w};
            const float br[4] = {b.x, b.y, b.z, b.w};
            #pragma unroll
            for (int i = 0; i < 4; ++i)
                #pragma unroll
                for (int j = 0; j < 4; ++j)
                    acc[i][j] = fmaf(ar[i], br[j], acc[i][j]);
        }
    }
    #pragma unroll
    for (int i = 0; i < 4; ++i) {
        const int r = r0 + tm * 4 + i;
        if (r >= M) continue;
        #pragma unroll
        for (int j = 0; j < 4; ++j) {
            const int cc = c0 + tn * 4 + j;
            float v = acc[i][j];
            if (mode == 1) {
                v += bias[cc];
                v = fmaxf(v, 0.f);
            }
            C[(size_t)r * 512 + cc] = v;
        }
    }
}

// one block per drug n: scores = (q[n] . rela[adj_rel[n,k]]) / sqrt(512),
// softmax over k, agg[n] = sum_k attn_k * ent[adj_tail[n,k]]
__global__ __launch_bounds__(256) void attn_kernel(
    const float* __restrict__ relaW, const float* __restrict__ entW,
    const int* __restrict__ adj_tail, const int* __restrict__ adj_rel,
    const float* __restrict__ q, float* __restrict__ agg)
{
    const int n = blockIdx.x;
    const int t = threadIdx.x;
    const int lane = t & 63;
    const int w = t >> 6;
    __shared__ float sc[64];
    __shared__ int tails[64];
    __shared__ int rels[64];
    if (t < 64) { tails[t] = adj_tail[n * 64 + t]; rels[t] = adj_rel[n * 64 + t]; }

    float qv[8];
    {
        const float4* p = (const float4*)(q + (size_t)n * 512 + lane * 8);
        float4 x = p[0], y = p[1];
        qv[0]=x.x; qv[1]=x.y; qv[2]=x.z; qv[3]=x.w;
        qv[4]=y.x; qv[5]=y.y; qv[6]=y.z; qv[7]=y.w;
    }
    __syncthreads();

    // each of the 4 waves computes 16 scores; each score is a 64-lane dot
    #pragma unroll 4
    for (int kk = 0; kk < 16; ++kk) {
        const int k = w * 16 + kk;
        const float4* p = (const float4*)(relaW + (size_t)rels[k] * 512 + lane * 8);
        float4 x = p[0], y = p[1];
        float s = 0.f;
        s = fmaf(qv[0], x.x, s); s = fmaf(qv[1], x.y, s);
        s = fmaf(qv[2], x.z, s); s = fmaf(qv[3], x.w, s);
        s = fmaf(qv[4], y.x, s); s = fmaf(qv[5], y.y, s);
        s = fmaf(qv[6], y.z, s); s = fmaf(qv[7], y.w, s);
        #pragma unroll
        for (int off = 32; off >= 1; off >>= 1) s += __shfl_xor(s, off, 64);
        if (lane == 0) sc[k] = s * 0.0441941738241592f;  // 1/sqrt(512)
    }
    __syncthreads();

    if (w == 0) {
        float s = sc[lane];
        float m = s;
        #pragma unroll
        for (int off = 32; off >= 1; off >>= 1) m = fmaxf(m, __shfl_xor(m, off, 64));
        const float e = __expf(s - m);
        float sum = e;
        #pragma unroll
        for (int off = 32; off >= 1; off >>= 1) sum += __shfl_xor(sum, off, 64);
        sc[lane] = e / sum;
    }
    __syncthreads();

    // agg: thread t covers columns 2t, 2t+1
    float a0 = 0.f, a1 = 0.f;
    const int d2 = t * 2;
    #pragma unroll 8
    for (int k = 0; k < 64; ++k) {
        const float ak = sc[k];
        const float2 u = *(const float2*)(entW + (size_t)tails[k] * 512 + d2);
        a0 = fmaf(ak, u.x, a0);
        a1 = fmaf(ak, u.y, a1);
    }
    ((float2*)(agg + (size_t)n * 512))[t] = make_float2(a0, a1);
}

// per-column mean/var over 572 rows -> fused scale/shift for BN
__global__ __launch_bounds__(256) void bn_stats_kernel(
    const float* __restrict__ h, const float* __restrict__ gamma,
    const float* __restrict__ beta, float* __restrict__ scale,
    float* __restrict__ shift)
{
    const int t = threadIdx.x;
    const int c = blockIdx.x * 64 + (t & 63);
    const int g = t >> 6;
    float s = 0.f, sq = 0.f;
    for (int r = g; r < N_DRUG; r += 4) {
        const float v = h[(size_t)r * 512 + c];
        s += v;
        sq = fmaf(v, v, sq);
    }
    __shared__ float S[4][64], Q[4][64];
    S[g][t & 63] = s; Q[g][t & 63] = sq;
    __syncthreads();
    if (t < 64) {
        const int cc = blockIdx.x * 64 + t;
        s  = S[0][t] + S[1][t] + S[2][t] + S[3][t];
        sq = Q[0][t] + Q[1][t] + Q[2][t] + Q[3][t];
        const float mean = s * (1.f / N_DRUG);
        const float var = sq * (1.f / N_DRUG) - mean * mean;
        const float rstd = rsqrtf(var + 1e-5f);
        const float ga = gamma[cc];
        scale[cc] = ga * rstd;
        shift[cc] = beta[cc] - mean * ga * rstd;
    }
}

// sequential smoothing scan, restructured:
//  - 32 blocks x 16 columns, 1 wave/block; BN'd slice fs[572+1][17] in LDS
//  - neighbor positions precomputed in LDS, dummy-padded to 32 (row 572 = 0)
//  - consecutive independent nodes grouped (up to 4) at setup via __ballot;
//    a group is processed in ONE round: lane (j4,c) = node gs+j4, column c,
//    sums all 32 neighbors itself -> no cross-lane reduce on the chain
//  - per-node (inv,wgt) precomputed -> branch-free update
// hout is BOTH the input h (read fully first) and the final output buffer.
__global__ __launch_bounds__(64) void scan_kernel(
    float* hout, const float* __restrict__ scale,
    const float* __restrict__ shift, const int* __restrict__ nbr_idx,
    const int* __restrict__ nbr_deg, const int* __restrict__ epoch)
{
    __shared__ float fs[(N_DRUG + 1) * FS_STRIDE];   // row 572 = zeros (dummy)
    __shared__ int   offs[N_DRUG * MAXDEG];          // neighbor row ids, dummy=572
    __shared__ float2 ivw[N_DRUG];                   // (inv, wgt) per node
    __shared__ int   gstart[N_DRUG + 4];             // group starts + sentinel
    __shared__ int   degs_s[N_DRUG];

    const int t = threadIdx.x;
    const int c = t & 15;
    const int j4 = t >> 4;
    const int c0 = blockIdx.x * 16;

    // --- stage degs, (inv,wgt), fs ---
    for (int i = t; i < N_DRUG; i += 64) {
        const int d = nbr_deg[i];
        degs_s[i] = d;
        ivw[i] = (d > 0) ? make_float2(0.5f / (float)d, 0.5f)
                         : make_float2(0.f, 1.f);
    }
    {
        const float scl = scale[c0 + c];
        const float shf = shift[c0 + c];
        for (int r = j4; r < N_DRUG; r += 4)
            fs[r * FS_STRIDE + c] = fmaf(hout[(size_t)r * 512 + c0 + c], scl, shf);
    }
    if (t < FS_STRIDE) fs[N_DRUG * FS_STRIDE + t] = 0.f;
    __syncthreads();

    // --- neighbor table, dummy-padded ---
    for (int e = t; e < N_DRUG * MAXDEG; e += 64) {
        const int pos = nbr_idx[e];
        offs[e] = ((e & 31) < degs_s[e >> 5]) ? pos : N_DRUG;
    }
    __syncthreads();

    if (epoch[0] > 1) {
        // --- grouping: consecutive nodes with no intra-group dependency ---
        const int m = t & 31;
        int G = 1;        // open group count; gstart[0] = 0
        int gs0 = 0;
        gstart[0] = 0;
        int pcur = offs[1 * MAXDEG + m];
        int pnxt = offs[2 * MAXDEG + m];
        for (int j = 1; j < N_DRUG; ++j) {
            const int pn = (j + 2 < N_DRUG) ? offs[(j + 2) * MAXDEG + m] : 0;
            const bool dep = (pcur >= gs0) && (pcur < j);
            if (__ballot(dep) != 0ULL || (j - gs0) == 4) {
                gstart[G] = j;
                G++;
                gs0 = j;
            }
            pcur = pnxt;
            pnxt = pn;
        }
        gstart[G] = N_DRUG;   // sentinel
        __syncthreads();

        // --- grouped scan: one round per group ---
        int gs = 0;
        int4 co[8];
        {
            const int4* p = (const int4*)&offs[min(j4, N_DRUG - 1) * MAXDEG];
            #pragma unroll
            for (int u = 0; u < 8; ++u) co[u] = p[u];
        }
        for (int r = 0; r < G; ++r) {
            const int ge = gstart[r + 1];
            const int gn = ge - gs;
            const int me = min(gs + j4, N_DRUG - 1);

            // issue all 32 neighbor-value reads (independent)
            float v[32];
            {
                const int idx[32] = {
                    co[0].x, co[0].y, co[0].z, co[0].w,
                    co[1].x, co[1].y, co[1].z, co[1].w,
                    co[2].x, co[2].y, co[2].z, co[2].w,
                    co[3].x, co[3].y, co[3].z, co[3].w,
                    co[4].x, co[4].y, co[4].z, co[4].w,
                    co[5].x, co[5].y, co[5].z, co[5].w,
                    co[6].x, co[6].y, co[6].z, co[6].w,
                    co[7].x, co[7].y, co[7].z, co[7].w };
                #pragma unroll
                for (int u = 0; u < 32; ++u)
                    v[u] = fs[idx[u] * FS_STRIDE + c];
            }
            // prefetch next group's offsets while the reads are in flight
            const int nxt = (r + 1 < G) ? ge : (N_DRUG - 1);
            int4 no[8];
            {
                const int4* p = (const int4*)&offs[min(nxt + j4, N_DRUG - 1) * MAXDEG];
                #pragma unroll
                for (int u = 0; u < 8; ++u) no[u] = p[u];
            }
            const float cur = fs[me * FS_STRIDE + c];
            const float2 iw = ivw[me];

            float p0 = 0.f, p1 = 0.f, p2 = 0.f, p3 = 0.f;
            #pragma unroll
            for (int u = 0; u < 8; ++u) {
                p0 += v[4 * u + 0];
                p1 += v[4 * u + 1];
                p2 += v[4 * u + 2];
                p3 += v[4 * u + 3];
            }
            const float s = (p0 + p1) + (p2 + p3);
            const float newv = fmaf(s, iw.x, cur * iw.y);

            if (j4 < gn) fs[(gs + j4) * FS_STRIDE + c] = newv;
            __syncthreads();

            gs = ge;
            #pragma unroll
            for (int u = 0; u < 8; ++u) co[u] = no[u];
        }
    }
    __syncthreads();
    for (int r = j4; r < N_DRUG; r += 4)
        hout[(size_t)r * 512 + c0 + c] = fs[r * FS_STRIDE + c];
}

extern "C" void kernel_launch(void* const* d_in, const int* in_sizes, int n_in,
                              void* d_out, int out_size, void* d_ws, size_t ws_size,
                              hipStream_t stream)
{
    const float* drugW = (const float*)d_in[0];
    const float* relaW = (const float*)d_in[1];
    const float* entW  = (const float*)d_in[2];
    const float* Wa    = (const float*)d_in[3];
    const float* linW  = (const float*)d_in[4];
    const float* linb  = (const float*)d_in[5];
    const float* gamma = (const float*)d_in[6];
    const float* beta  = (const float*)d_in[7];
    const int* drug_name = (const int*)d_in[8];
    const int* adj_tail  = (const int*)d_in[9];
    const int* adj_rel   = (const int*)d_in[10];
    const int* nbr_idx   = (const int*)d_in[11];
    const int* nbr_deg   = (const int*)d_in[12];
    const int* epoch     = (const int*)d_in[13];

    float* ws = (float*)d_ws;
    float* q     = ws;                              // [572,512]
    float* agg   = ws + (size_t)N_DRUG * 512;       // [572,512]
    float* scale = ws + (size_t)2 * N_DRUG * 512;   // [512]
    float* shift = scale + 512;                     // [512]
    float* h = (float*)d_out;                       // h lives in d_out, overwritten in-place by scan

    dim3 ggrid(8, 9);
    gemm_kernel<<<ggrid, 256, 0, stream>>>(drugW, drug_name, nullptr, Wa, nullptr, q,
                                           N_DRUG, 512, 0);
    attn_kernel<<<N_DRUG, 256, 0, stream>>>(relaW, entW, adj_tail, adj_rel, q, agg);
    gemm_kernel<<<ggrid, 256, 0, stream>>>(drugW, drug_name, agg, linW, linb, h,
                                           N_DRUG, 1024, 1);
    bn_stats_kernel<<<8, 256, 0, stream>>>(h, gamma, beta, scale, shift);
    scan_kernel<<<32, 64, 0, stream>>>(h, scale, shift, nbr_idx, nbr_deg, epoch);
}

// Round 4
// 303.920 us; speedup vs baseline: 2.2278x; 1.2437x over previous
//
#include <hip/hip_runtime.h>

#define N_DRUG 572
#define DIM 512
#define KNBR 64
#define MAXDEG 32
#define FS 17   // 16 cols + 1 pad

// C[M x 512] = A[M x Kdim] @ B[Kdim x 512]; A is gathered/mixed per mode.
// mode 0: A = drugW[drug_name[r]][k]            (Kdim=512), no epilogue
// mode 1: A = k<512 ? agg[r][k] : drugW[drug_name[r]][k-512] (Kdim=1024),
//         epilogue: +bias, ReLU
__global__ __launch_bounds__(256) void gemm_kernel(
    const float* __restrict__ drugW, const int* __restrict__ drug_name,
    const float* __restrict__ agg, const float* __restrict__ B,
    const float* __restrict__ bias, float* __restrict__ C,
    int M, int Kdim, int mode)
{
    __shared__ float As[32][64];   // transposed: As[k][m]
    __shared__ float Bs[32][64];   // Bs[k][c]
    const int t = threadIdx.x;
    const int c0 = blockIdx.x * 64;
    const int r0 = blockIdx.y * 64;
    const int tn = t & 15, tm = t >> 4;
    const int am = t & 63, ak0 = (t >> 6) * 8;
    const int bk = t >> 3, bc = (t & 7) * 8;
    const int arow = r0 + am;

    float acc[4][4] = {{0.f}};

    for (int ks = 0; ks < Kdim; ks += 32) {
        float av[8], bv[8];
        if (arow < M) {
            const int k = ks + ak0;
            const float* src;
            if (mode == 1 && k < 512) {
                src = agg + (size_t)arow * 512 + k;
            } else {
                const int kk2 = (mode == 1) ? (k - 512) : k;
                src = drugW + (size_t)drug_name[arow] * 512 + kk2;
            }
            const float4 x = ((const float4*)src)[0];
            const float4 y = ((const float4*)src)[1];
            av[0]=x.x; av[1]=x.y; av[2]=x.z; av[3]=x.w;
            av[4]=y.x; av[5]=y.y; av[6]=y.z; av[7]=y.w;
        } else {
            #pragma unroll
            for (int j = 0; j < 8; ++j) av[j] = 0.f;
        }
        {
            const float* src = B + (size_t)(ks + bk) * 512 + c0 + bc;
            const float4 x = ((const float4*)src)[0];
            const float4 y = ((const float4*)src)[1];
            bv[0]=x.x; bv[1]=x.y; bv[2]=x.z; bv[3]=x.w;
            bv[4]=y.x; bv[5]=y.y; bv[6]=y.z; bv[7]=y.w;
        }

        __syncthreads();
        #pragma unroll
        for (int j = 0; j < 8; ++j) As[ak0 + j][am] = av[j];
        #pragma unroll
        for (int j = 0; j < 8; ++j) Bs[bk][bc + j] = bv[j];
        __syncthreads();

        #pragma unroll
        for (int kk = 0; kk < 32; ++kk) {
            const float4 a = *(const float4*)&As[kk][tm * 4];
            const float4 b = *(const float4*)&Bs[kk][tn * 4];
            const float ar[4] = {a.x, a.y, a.z, a.w};
            const float br[4] = {b.x, b.y, b.z, b.w};
            #pragma unroll
            for (int i = 0; i < 4; ++i)
                #pragma unroll
                for (int j = 0; j < 4; ++j)
                    acc[i][j] = fmaf(ar[i], br[j], acc[i][j]);
        }
    }
    #pragma unroll
    for (int i = 0; i < 4; ++i) {
        const int r = r0 + tm * 4 + i;
        if (r >= M) continue;
        #pragma unroll
        for (int j = 0; j < 4; ++j) {
            const int cc = c0 + tn * 4 + j;
            float v = acc[i][j];
            if (mode == 1) {
                v += bias[cc];
                v = fmaxf(v, 0.f);
            }
            C[(size_t)r * 512 + cc] = v;
        }
    }
}

// one block per drug n: scores = (q[n] . rela[adj_rel[n,k]]) / sqrt(512),
// softmax over k, agg[n] = sum_k attn_k * ent[adj_tail[n,k]]
__global__ __launch_bounds__(256) void attn_kernel(
    const float* __restrict__ relaW, const float* __restrict__ entW,
    const int* __restrict__ adj_tail, const int* __restrict__ adj_rel,
    const float* __restrict__ q, float* __restrict__ agg)
{
    const int n = blockIdx.x;
    const int t = threadIdx.x;
    const int lane = t & 63;
    const int w = t >> 6;
    __shared__ float sc[64];
    __shared__ int tails[64];
    __shared__ int rels[64];
    if (t < 64) { tails[t] = adj_tail[n * 64 + t]; rels[t] = adj_rel[n * 64 + t]; }

    float qv[8];
    {
        const float4* p = (const float4*)(q + (size_t)n * 512 + lane * 8);
        float4 x = p[0], y = p[1];
        qv[0]=x.x; qv[1]=x.y; qv[2]=x.z; qv[3]=x.w;
        qv[4]=y.x; qv[5]=y.y; qv[6]=y.z; qv[7]=y.w;
    }
    __syncthreads();

    #pragma unroll 4
    for (int kk = 0; kk < 16; ++kk) {
        const int k = w * 16 + kk;
        const float4* p = (const float4*)(relaW + (size_t)rels[k] * 512 + lane * 8);
        float4 x = p[0], y = p[1];
        float s = 0.f;
        s = fmaf(qv[0], x.x, s); s = fmaf(qv[1], x.y, s);
        s = fmaf(qv[2], x.z, s); s = fmaf(qv[3], x.w, s);
        s = fmaf(qv[4], y.x, s); s = fmaf(qv[5], y.y, s);
        s = fmaf(qv[6], y.z, s); s = fmaf(qv[7], y.w, s);
        #pragma unroll
        for (int off = 32; off >= 1; off >>= 1) s += __shfl_xor(s, off, 64);
        if (lane == 0) sc[k] = s * 0.0441941738241592f;  // 1/sqrt(512)
    }
    __syncthreads();

    if (w == 0) {
        float s = sc[lane];
        float m = s;
        #pragma unroll
        for (int off = 32; off >= 1; off >>= 1) m = fmaxf(m, __shfl_xor(m, off, 64));
        const float e = __expf(s - m);
        float sum = e;
        #pragma unroll
        for (int off = 32; off >= 1; off >>= 1) sum += __shfl_xor(sum, off, 64);
        sc[lane] = e / sum;
    }
    __syncthreads();

    float a0 = 0.f, a1 = 0.f;
    const int d2 = t * 2;
    #pragma unroll 8
    for (int k = 0; k < 64; ++k) {
        const float ak = sc[k];
        const float2 u = *(const float2*)(entW + (size_t)tails[k] * 512 + d2);
        a0 = fmaf(ak, u.x, a0);
        a1 = fmaf(ak, u.y, a1);
    }
    ((float2*)(agg + (size_t)n * 512))[t] = make_float2(a0, a1);
}

// Fused BN + sequential smoothing scan.
// 32 blocks x 16 cols, 256 threads (4 waves). Thread = (node j4, col c).
// - stage fs slice + column stats; BN scale/shift computed in-kernel
// - lookback lb[j] = distance to nearest dependency below j (parallel)
// - wave0 runs the serial group-break scan (cap 16) WHILE waves1-3 apply BN
// - per round: 16 nodes processed; each thread sums its node's 32 padded
//   neighbors from named int4 regs; barriers protect anti-deps across waves
__global__ __launch_bounds__(256) void scan_kernel(
    float* hout, const float* __restrict__ gamma, const float* __restrict__ beta,
    const int* __restrict__ nbr_idx, const int* __restrict__ nbr_deg,
    const int* __restrict__ epoch)
{
    __shared__ float fs[(N_DRUG + 1) * FS];      // row N_DRUG = zeros (dummy)
    __shared__ int   offs[N_DRUG * MAXDEG];      // padded neighbor rows (dummy=N_DRUG)
    __shared__ float2 ivw[N_DRUG];               // (0.5/deg, 0.5) or (0,1)
    __shared__ int   lbs[N_DRUG];                // lookback distance
    __shared__ int   gstart[N_DRUG + 8];
    __shared__ float part[2][16][16];
    __shared__ int   gcount;

    const int t = threadIdx.x;
    const int c = t & 15;
    const int j4 = t >> 4;
    const int c0 = blockIdx.x * 16;

    // ---- phase 0a: neighbor table, lookback, ivw ----
    for (int i = t; i < N_DRUG; i += 256) {
        const int d = nbr_deg[i];
        ivw[i] = (d > 0) ? make_float2(0.5f / (float)d, 0.5f) : make_float2(0.f, 1.f);
        const int4* np = (const int4*)&nbr_idx[i * MAXDEG];
        int4* op = (int4*)&offs[i * MAXDEG];
        int mx = -1;
        #pragma unroll
        for (int u = 0; u < 8; ++u) {
            int4 qq = np[u];
            const int b = u * 4;
            qq.x = (b + 0 < d) ? qq.x : N_DRUG;
            qq.y = (b + 1 < d) ? qq.y : N_DRUG;
            qq.z = (b + 2 < d) ? qq.z : N_DRUG;
            qq.w = (b + 3 < d) ? qq.w : N_DRUG;
            mx = max(mx, (qq.x < i) ? qq.x : -1);
            mx = max(mx, (qq.y < i) ? qq.y : -1);
            mx = max(mx, (qq.z < i) ? qq.z : -1);
            mx = max(mx, (qq.w < i) ? qq.w : -1);
            op[u] = qq;
        }
        lbs[i] = (mx >= 0) ? (i - mx) : (1 << 20);
    }

    // ---- phase 0b: stage fs + per-(j4,c) partial stats ----
    {
        float sl = 0.f, ql = 0.f;
        for (int r = j4; r < N_DRUG; r += 16) {
            const float v = hout[(size_t)r * DIM + c0 + c];
            fs[r * FS + c] = v;
            sl += v;
            ql = fmaf(v, v, ql);
        }
        part[0][j4][c] = sl;
        part[1][j4][c] = ql;
    }
    if (t < FS) fs[N_DRUG * FS + t] = 0.f;
    __syncthreads();

    const int ep = epoch[0];

    // ---- phase 1: (wave0) group-break scan  ||  (waves1-3) BN finalize+apply ----
    if (t >= 64) {
        float s = 0.f, sq = 0.f;
        #pragma unroll
        for (int k = 0; k < 16; ++k) { s += part[0][k][c]; sq += part[1][k][c]; }
        const float mean = s * (1.f / N_DRUG);
        const float var = sq * (1.f / N_DRUG) - mean * mean;
        const float rstd = rsqrtf(var + 1e-5f);
        const float scl = gamma[c0 + c] * rstd;
        const float shf = beta[c0 + c] - mean * scl;
        for (int r = (t - 64) >> 4; r < N_DRUG; r += 12)
            fs[r * FS + c] = fmaf(fs[r * FS + c], scl, shf);
    } else if (ep > 1) {
        // uniform across the 64 lanes; 4-deep rolling prefetch of lbs
        int G = 1, g = 0;
        gstart[0] = 0;
        int l0 = lbs[1], l1 = lbs[2], l2 = lbs[3], l3 = lbs[4];
        for (int j = 1; j < N_DRUG; ++j) {
            const int ln = (j + 4 < N_DRUG) ? lbs[j + 4] : (1 << 20);
            if ((l0 <= j - g) | ((j - g) >= 16)) { gstart[G] = j; ++G; g = j; }
            l0 = l1; l1 = l2; l2 = l3; l3 = ln;
        }
        gstart[G] = N_DRUG;
        if (t == 0) gcount = G;
    }

    // prefetch group-0 offsets (offs is stable after phase 0)
    int4 co0, co1, co2, co3, co4, co5, co6, co7;
    {
        const int4* p = (const int4*)&offs[min(j4, N_DRUG - 1) * MAXDEG];
        co0 = p[0]; co1 = p[1]; co2 = p[2]; co3 = p[3];
        co4 = p[4]; co5 = p[5]; co6 = p[6]; co7 = p[7];
    }
    __syncthreads();

    // ---- rounds ----
    if (ep > 1) {
        const int G = gcount;
        int gs = 0;
        for (int r = 0; r < G; ++r) {
            const int ge = gstart[r + 1];
            float s0 = 0.f, s1 = 0.f, s2 = 0.f, s3 = 0.f;
#define GATH(Q) \
            s0 += fs[Q.x * FS + c]; s1 += fs[Q.y * FS + c]; \
            s2 += fs[Q.z * FS + c]; s3 += fs[Q.w * FS + c];
            GATH(co0) GATH(co1) GATH(co2) GATH(co3)
            GATH(co4) GATH(co5) GATH(co6) GATH(co7)
#undef GATH
            // prefetch next group's offsets while gathers are in flight
            int4 no0, no1, no2, no3, no4, no5, no6, no7;
            {
                const int4* p = (const int4*)&offs[min(ge + j4, N_DRUG - 1) * MAXDEG];
                no0 = p[0]; no1 = p[1]; no2 = p[2]; no3 = p[3];
                no4 = p[4]; no5 = p[5]; no6 = p[6]; no7 = p[7];
            }
            const int me = min(gs + j4, ge - 1);
            const float cur = fs[me * FS + c];
            const float2 iw = ivw[me];
            const float newv = fmaf((s0 + s1) + (s2 + s3), iw.x, cur * iw.y);
            __syncthreads();   // all reads done before any write (anti-deps)
            if (gs + j4 < ge) fs[(gs + j4) * FS + c] = newv;
            __syncthreads();   // writes visible before next round's gathers
            gs = ge;
            co0 = no0; co1 = no1; co2 = no2; co3 = no3;
            co4 = no4; co5 = no5; co6 = no6; co7 = no7;
        }
    }
    __syncthreads();

    // ---- write back ----
    for (int r = j4; r < N_DRUG; r += 16)
        hout[(size_t)r * DIM + c0 + c] = fs[r * FS + c];
}

extern "C" void kernel_launch(void* const* d_in, const int* in_sizes, int n_in,
                              void* d_out, int out_size, void* d_ws, size_t ws_size,
                              hipStream_t stream)
{
    const float* drugW = (const float*)d_in[0];
    const float* relaW = (const float*)d_in[1];
    const float* entW  = (const float*)d_in[2];
    const float* Wa    = (const float*)d_in[3];
    const float* linW  = (const float*)d_in[4];
    const float* linb  = (const float*)d_in[5];
    const float* gamma = (const float*)d_in[6];
    const float* beta  = (const float*)d_in[7];
    const int* drug_name = (const int*)d_in[8];
    const int* adj_tail  = (const int*)d_in[9];
    const int* adj_rel   = (const int*)d_in[10];
    const int* nbr_idx   = (const int*)d_in[11];
    const int* nbr_deg   = (const int*)d_in[12];
    const int* epoch     = (const int*)d_in[13];

    float* ws = (float*)d_ws;
    float* q   = ws;                              // [572,512]
    float* agg = ws + (size_t)N_DRUG * 512;       // [572,512]
    float* h = (float*)d_out;                     // h in d_out; scan updates in place

    dim3 ggrid(8, 9);
    gemm_kernel<<<ggrid, 256, 0, stream>>>(drugW, drug_name, nullptr, Wa, nullptr, q,
                                           N_DRUG, 512, 0);
    attn_kernel<<<N_DRUG, 256, 0, stream>>>(relaW, entW, adj_tail, adj_rel, q, agg);
    gemm_kernel<<<ggrid, 256, 0, stream>>>(drugW, drug_name, agg, linW, linb, h,
                                           N_DRUG, 1024, 1);
    scan_kernel<<<32, 256, 0, stream>>>(h, gamma, beta, nbr_idx, nbr_deg, epoch);
}

// Round 5
// 263.918 us; speedup vs baseline: 2.5655x; 1.1516x over previous
//
#include <hip/hip_runtime.h>

#define N_DRUG 572
#define DIM 512
#define KNBR 64
#define MAXDEG 32
#define FS 17   // 16 cols + 1 pad

// C[M x 512] = A[M x Kdim] @ B[Kdim x 512]; A is gathered/mixed per mode.
// mode 0: A = drugW[drug_name[r]][k]            (Kdim=512), no epilogue
// mode 1: A = k<512 ? agg[r][k] : drugW[drug_name[r]][k-512] (Kdim=1024),
//         epilogue: +bias, ReLU
__global__ __launch_bounds__(256) void gemm_kernel(
    const float* __restrict__ drugW, const int* __restrict__ drug_name,
    const float* __restrict__ agg, const float* __restrict__ B,
    const float* __restrict__ bias, float* __restrict__ C,
    int M, int Kdim, int mode)
{
    __shared__ float As[32][64];   // transposed: As[k][m]
    __shared__ float Bs[32][64];   // Bs[k][c]
    const int t = threadIdx.x;
    const int c0 = blockIdx.x * 64;
    const int r0 = blockIdx.y * 64;
    const int tn = t & 15, tm = t >> 4;
    const int am = t & 63, ak0 = (t >> 6) * 8;
    const int bk = t >> 3, bc = (t & 7) * 8;
    const int arow = r0 + am;

    float acc[4][4] = {{0.f}};

    for (int ks = 0; ks < Kdim; ks += 32) {
        float av[8], bv[8];
        if (arow < M) {
            const int k = ks + ak0;
            const float* src;
            if (mode == 1 && k < 512) {
                src = agg + (size_t)arow * 512 + k;
            } else {
                const int kk2 = (mode == 1) ? (k - 512) : k;
                src = drugW + (size_t)drug_name[arow] * 512 + kk2;
            }
            const float4 x = ((const float4*)src)[0];
            const float4 y = ((const float4*)src)[1];
            av[0]=x.x; av[1]=x.y; av[2]=x.z; av[3]=x.w;
            av[4]=y.x; av[5]=y.y; av[6]=y.z; av[7]=y.w;
        } else {
            #pragma unroll
            for (int j = 0; j < 8; ++j) av[j] = 0.f;
        }
        {
            const float* src = B + (size_t)(ks + bk) * 512 + c0 + bc;
            const float4 x = ((const float4*)src)[0];
            const float4 y = ((const float4*)src)[1];
            bv[0]=x.x; bv[1]=x.y; bv[2]=x.z; bv[3]=x.w;
            bv[4]=y.x; bv[5]=y.y; bv[6]=y.z; bv[7]=y.w;
        }

        __syncthreads();
        #pragma unroll
        for (int j = 0; j < 8; ++j) As[ak0 + j][am] = av[j];
        #pragma unroll
        for (int j = 0; j < 8; ++j) Bs[bk][bc + j] = bv[j];
        __syncthreads();

        #pragma unroll
        for (int kk = 0; kk < 32; ++kk) {
            const float4 a = *(const float4*)&As[kk][tm * 4];
            const float4 b = *(const float4*)&Bs[kk][tn * 4];
            const float ar[4] = {a.x, a.y, a.z, a.w};
            const float br[4] = {b.x, b.y, b.z, b.w};
            #pragma unroll
            for (int i = 0; i < 4; ++i)
                #pragma unroll
                for (int j = 0; j < 4; ++j)
                    acc[i][j] = fmaf(ar[i], br[j], acc[i][j]);
        }
    }
    #pragma unroll
    for (int i = 0; i < 4; ++i) {
        const int r = r0 + tm * 4 + i;
        if (r >= M) continue;
        #pragma unroll
        for (int j = 0; j < 4; ++j) {
            const int cc = c0 + tn * 4 + j;
            float v = acc[i][j];
            if (mode == 1) {
                v += bias[cc];
                v = fmaxf(v, 0.f);
            }
            C[(size_t)r * 512 + cc] = v;
        }
    }
}

// one block per drug n: scores = (q[n] . rela[adj_rel[n,k]]) / sqrt(512),
// softmax over k, agg[n] = sum_k attn_k * ent[adj_tail[n,k]]
__global__ __launch_bounds__(256) void attn_kernel(
    const float* __restrict__ relaW, const float* __restrict__ entW,
    const int* __restrict__ adj_tail, const int* __restrict__ adj_rel,
    const float* __restrict__ q, float* __restrict__ agg)
{
    const int n = blockIdx.x;
    const int t = threadIdx.x;
    const int lane = t & 63;
    const int w = t >> 6;
    __shared__ float sc[64];
    __shared__ int tails[64];
    __shared__ int rels[64];
    if (t < 64) { tails[t] = adj_tail[n * 64 + t]; rels[t] = adj_rel[n * 64 + t]; }

    float qv[8];
    {
        const float4* p = (const float4*)(q + (size_t)n * 512 + lane * 8);
        float4 x = p[0], y = p[1];
        qv[0]=x.x; qv[1]=x.y; qv[2]=x.z; qv[3]=x.w;
        qv[4]=y.x; qv[5]=y.y; qv[6]=y.z; qv[7]=y.w;
    }
    __syncthreads();

    #pragma unroll 4
    for (int kk = 0; kk < 16; ++kk) {
        const int k = w * 16 + kk;
        const float4* p = (const float4*)(relaW + (size_t)rels[k] * 512 + lane * 8);
        float4 x = p[0], y = p[1];
        float s = 0.f;
        s = fmaf(qv[0], x.x, s); s = fmaf(qv[1], x.y, s);
        s = fmaf(qv[2], x.z, s); s = fmaf(qv[3], x.w, s);
        s = fmaf(qv[4], y.x, s); s = fmaf(qv[5], y.y, s);
        s = fmaf(qv[6], y.z, s); s = fmaf(qv[7], y.w, s);
        #pragma unroll
        for (int off = 32; off >= 1; off >>= 1) s += __shfl_xor(s, off, 64);
        if (lane == 0) sc[k] = s * 0.0441941738241592f;  // 1/sqrt(512)
    }
    __syncthreads();

    if (w == 0) {
        float s = sc[lane];
        float m = s;
        #pragma unroll
        for (int off = 32; off >= 1; off >>= 1) m = fmaxf(m, __shfl_xor(m, off, 64));
        const float e = __expf(s - m);
        float sum = e;
        #pragma unroll
        for (int off = 32; off >= 1; off >>= 1) sum += __shfl_xor(sum, off, 64);
        sc[lane] = e / sum;
    }
    __syncthreads();

    float a0 = 0.f, a1 = 0.f;
    const int d2 = t * 2;
    #pragma unroll 8
    for (int k = 0; k < 64; ++k) {
        const float ak = sc[k];
        const float2 u = *(const float2*)(entW + (size_t)tails[k] * 512 + d2);
        a0 = fmaf(ak, u.x, a0);
        a1 = fmaf(ak, u.y, a1);
    }
    ((float2*)(agg + (size_t)n * 512))[t] = make_float2(a0, a1);
}

// Fused BN + sequential smoothing scan.
// 32 blocks x 16 cols, 512 threads (8 waves).
// Thread = (node j = t>>5 in 0..15, half h = (t>>4)&1, col c = t&15):
// each thread sums 16 of its node's 32 padded neighbors; one shfl_xor(16)
// combines halves. Inactive nodes (beyond current group) skip all DS work.
// Group boundaries computed ON THE FLY by wave 7 (window test on mx[] +
// ballot/ctz), double-buffered through LDS -> no serial grouping pass.
__global__ __launch_bounds__(512) void scan_kernel(
    float* hout, const float* __restrict__ gamma, const float* __restrict__ beta,
    const int* __restrict__ nbr_idx, const int* __restrict__ nbr_deg,
    const int* __restrict__ epoch)
{
    __shared__ float fs[(N_DRUG + 1) * FS];      // row N_DRUG = zeros (dummy)
    __shared__ int   offs[N_DRUG * MAXDEG];      // padded neighbor rows (dummy=N_DRUG)
    __shared__ float2 ivw[N_DRUG];               // (0.5/deg, 0.5) or (0,1)
    __shared__ int   mxs[N_DRUG];                // max lower-dep row, -1 if none
    __shared__ float part[2][32][16];            // stats partials [s|q][rr][c]
    __shared__ float bnp[2][16];                 // scl, shf per col
    __shared__ int   genext[2];
    __shared__ int   ge0s;

    const int t  = threadIdx.x;
    const int c  = t & 15;
    const int h  = (t >> 4) & 1;
    const int j  = t >> 5;         // node slot 0..15
    const int rr = t >> 4;         // staging row-group 0..31
    const int c0 = blockIdx.x * 16;

    // ---- phase 0a: neighbor table (padded), mx, ivw ----
    for (int i = t; i < N_DRUG; i += 512) {
        const int d = nbr_deg[i];
        ivw[i] = (d > 0) ? make_float2(0.5f / (float)d, 0.5f) : make_float2(0.f, 1.f);
        const int4* np = (const int4*)&nbr_idx[i * MAXDEG];
        int4* op = (int4*)&offs[i * MAXDEG];
        int mx = -1;
        #pragma unroll
        for (int u = 0; u < 8; ++u) {
            int4 qq = np[u];
            const int b = u * 4;
            qq.x = (b + 0 < d) ? qq.x : N_DRUG;
            qq.y = (b + 1 < d) ? qq.y : N_DRUG;
            qq.z = (b + 2 < d) ? qq.z : N_DRUG;
            qq.w = (b + 3 < d) ? qq.w : N_DRUG;
            mx = max(mx, (qq.x < i) ? qq.x : -1);
            mx = max(mx, (qq.y < i) ? qq.y : -1);
            mx = max(mx, (qq.z < i) ? qq.z : -1);
            mx = max(mx, (qq.w < i) ? qq.w : -1);
            op[u] = qq;
        }
        mxs[i] = mx;
    }

    // ---- phase 0b: stage fs + per-(rr,c) partial stats ----
    {
        float sl = 0.f, ql = 0.f;
        for (int r = rr; r < N_DRUG; r += 32) {
            const float v = hout[(size_t)r * DIM + c0 + c];
            fs[r * FS + c] = v;
            sl += v;
            ql = fmaf(v, v, ql);
        }
        part[0][rr][c] = sl;
        part[1][rr][c] = ql;
    }
    if (t < FS) fs[N_DRUG * FS + t] = 0.f;
    __syncthreads();

    // ---- phase 1: stats finalize (t<16) || first group boundary (wave 7) ----
    if (t < 16) {
        float s = 0.f, sq = 0.f;
        #pragma unroll
        for (int k = 0; k < 32; ++k) { s += part[0][k][t]; sq += part[1][k][t]; }
        const float mean = s * (1.f / N_DRUG);
        const float var = sq * (1.f / N_DRUG) - mean * mean;
        const float rstd = rsqrtf(var + 1e-5f);
        const float scl = gamma[c0 + t] * rstd;
        bnp[0][t] = scl;
        bnp[1][t] = beta[c0 + t] - mean * scl;
    }
    if ((t >> 6) == 7) {
        const int l = t & 63;
        const int jj = 1 + l;
        const bool flag = (l >= 15) || (jj >= N_DRUG) || (mxs[min(jj, N_DRUG - 1)] >= 0);
        const unsigned long long b = __ballot(flag) & 0xFFFFULL;
        if (l == 0) ge0s = 1 + (int)__builtin_ctzll(b);
    }
    __syncthreads();

    // ---- phase 2: BN apply ----
    {
        const float scl = bnp[0][c];
        const float shf = bnp[1][c];
        for (int r = rr; r < N_DRUG; r += 32)
            fs[r * FS + c] = fmaf(fs[r * FS + c], scl, shf);
    }
    __syncthreads();

    // ---- rounds ----
    if (epoch[0] > 1) {
        int gs = 0, ge = ge0s;
        int4 o0, o1, o2, o3;
        {
            const int4* p = (const int4*)&offs[min(j, N_DRUG - 1) * MAXDEG + h * 16];
            o0 = p[0]; o1 = p[1]; o2 = p[2]; o3 = p[3];
        }
        int par = 0;
        while (gs < N_DRUG) {
            const bool pred = (gs + j) < ge;
            float s0 = 0.f, s1 = 0.f, s2 = 0.f, s3 = 0.f;
#define GATH4(Q) { s0 += fs[Q.x * FS + c]; s1 += fs[Q.y * FS + c]; \
                   s2 += fs[Q.z * FS + c]; s3 += fs[Q.w * FS + c]; }
            if (pred) { GATH4(o0) GATH4(o1) GATH4(o2) GATH4(o3) }
#undef GATH4
            // prefetch next group's offsets (next group starts at ge)
            int4 n0, n1, n2, n3;
            {
                const int4* p = (const int4*)&offs[min(ge + j, N_DRUG - 1) * MAXDEG + h * 16];
                n0 = p[0]; n1 = p[1]; n2 = p[2]; n3 = p[3];
            }
            float nv = 0.f;
            if (pred) {
                const float cur = fs[(gs + j) * FS + c];
                const float2 iw = ivw[gs + j];
                float sh = (s0 + s1) + (s2 + s3);
                sh += __shfl_xor(sh, 16, 64);    // combine the two halves
                nv = fmaf(sh, iw.x, cur * iw.y);
            }
            // wave 7: compute the NEXT group end while gathers are in flight
            if ((t >> 6) == 7) {
                const int l = t & 63;
                const int jj = ge + 1 + l;
                const bool flag = (l >= 15) || (jj >= N_DRUG) ||
                                  (mxs[min(jj, N_DRUG - 1)] >= ge);
                const unsigned long long b = __ballot(flag) & 0xFFFFULL;
                if (l == 0) genext[par] = ge + 1 + (int)__builtin_ctzll(b);
            }
            __syncthreads();   // all reads done before any write (anti-deps)
            if (pred && h == 0) fs[(gs + j) * FS + c] = nv;
            __syncthreads();   // writes + genext visible
            gs = ge;
            ge = genext[par];
            par ^= 1;
            o0 = n0; o1 = n1; o2 = n2; o3 = n3;
        }
    }
    __syncthreads();

    // ---- write back ----
    for (int r = rr; r < N_DRUG; r += 32)
        hout[(size_t)r * DIM + c0 + c] = fs[r * FS + c];
}

extern "C" void kernel_launch(void* const* d_in, const int* in_sizes, int n_in,
                              void* d_out, int out_size, void* d_ws, size_t ws_size,
                              hipStream_t stream)
{
    const float* drugW = (const float*)d_in[0];
    const float* relaW = (const float*)d_in[1];
    const float* entW  = (const float*)d_in[2];
    const float* Wa    = (const float*)d_in[3];
    const float* linW  = (const float*)d_in[4];
    const float* linb  = (const float*)d_in[5];
    const float* gamma = (const float*)d_in[6];
    const float* beta  = (const float*)d_in[7];
    const int* drug_name = (const int*)d_in[8];
    const int* adj_tail  = (const int*)d_in[9];
    const int* adj_rel   = (const int*)d_in[10];
    const int* nbr_idx   = (const int*)d_in[11];
    const int* nbr_deg   = (const int*)d_in[12];
    const int* epoch     = (const int*)d_in[13];

    float* ws = (float*)d_ws;
    float* q   = ws;                              // [572,512]
    float* agg = ws + (size_t)N_DRUG * 512;       // [572,512]
    float* h = (float*)d_out;                     // h in d_out; scan updates in place

    dim3 ggrid(8, 9);
    gemm_kernel<<<ggrid, 256, 0, stream>>>(drugW, drug_name, nullptr, Wa, nullptr, q,
                                           N_DRUG, 512, 0);
    attn_kernel<<<N_DRUG, 256, 0, stream>>>(relaW, entW, adj_tail, adj_rel, q, agg);
    gemm_kernel<<<ggrid, 256, 0, stream>>>(drugW, drug_name, agg, linW, linb, h,
                                           N_DRUG, 1024, 1);
    scan_kernel<<<32, 512, 0, stream>>>(h, gamma, beta, nbr_idx, nbr_deg, epoch);
}

// Round 6
// 226.147 us; speedup vs baseline: 2.9940x; 1.1670x over previous
//
#include <hip/hip_runtime.h>

#define N_DRUG 572
#define DIM 512
#define KNBR 64
#define MAXDEG 32
#define FS 17            // scan LDS stride: 16 cols + 1 pad
#define MN (N_DRUG * DIM)   // 292864
#define LSTR 68          // gemm LDS stride (words): 16B-aligned rows, odd/4 banks

// C[kc][M x 512] partial = A[M x Kslice] @ B[Kslice x 512]
// mode 0: A = drugW[drug_name[r]][k]
// mode 1: A = k<512 ? agg[r][k] : drugW[drug_name[r]][k-512]
// Kc = K elements per split-K chunk; blockIdx.z = chunk id.
// Double-buffered LDS, register prefetch, 64x64 tile, 4x4 micro-tile.
__global__ __launch_bounds__(256) void gemm_kernel(
    const float* __restrict__ drugW, const int* __restrict__ drug_name,
    const float* __restrict__ agg, const float* __restrict__ B,
    float* __restrict__ C, int M, int Kc, int mode)
{
    __shared__ float As[2][32 * LSTR];
    __shared__ float Bs[2][32 * LSTR];
    const int t   = threadIdx.x;
    const int tn  = t & 15, tm = t >> 4;          // compute: 4 cols, 4 rows each
    const int arow = t & 63, akq = (t >> 6) * 8;  // A load: row, k-chunk of 8
    const int brow = t >> 3, bcq = (t & 7) * 8;   // B load: k-row, col-chunk of 8
    const int c0  = blockIdx.x * 64;
    const int r0  = blockIdx.y * 64;
    const int ks0 = blockIdx.z * Kc;
    const int nsteps = Kc >> 5;
    const int row = r0 + arow;
    const bool aval = row < M;
    const int dn = aval ? drug_name[row] : 0;
    const float* __restrict__ drow = drugW + (size_t)dn * 512;
    const float* __restrict__ grow = agg + (size_t)row * 512;

    float av[8], bv[8];
    float acc[4][4] = {{0.f}};

    // ---- prologue: load + stage tile 0 ----
    {
        const int k = ks0 + akq;
        if (aval) {
            const float* src = (mode == 1) ? ((k < 512) ? (grow + k) : (drow + (k - 512)))
                                           : (drow + k);
            const float4 x = ((const float4*)src)[0];
            const float4 y = ((const float4*)src)[1];
            av[0]=x.x; av[1]=x.y; av[2]=x.z; av[3]=x.w;
            av[4]=y.x; av[5]=y.y; av[6]=y.z; av[7]=y.w;
        } else {
            #pragma unroll
            for (int j = 0; j < 8; ++j) av[j] = 0.f;
        }
        const float* bsrc = B + (size_t)(ks0 + brow) * 512 + c0 + bcq;
        const float4 x = ((const float4*)bsrc)[0];
        const float4 y = ((const float4*)bsrc)[1];
        bv[0]=x.x; bv[1]=x.y; bv[2]=x.z; bv[3]=x.w;
        bv[4]=y.x; bv[5]=y.y; bv[6]=y.z; bv[7]=y.w;
    }
    #pragma unroll
    for (int i = 0; i < 8; ++i) As[0][(akq + i) * LSTR + arow] = av[i];
    *(float4*)&Bs[0][brow * LSTR + bcq]     = make_float4(bv[0], bv[1], bv[2], bv[3]);
    *(float4*)&Bs[0][brow * LSTR + bcq + 4] = make_float4(bv[4], bv[5], bv[6], bv[7]);
    __syncthreads();

    int p = 0;
    for (int s = 0; s < nsteps; ++s) {
        const bool more = (s + 1) < nsteps;
        if (more) {   // register prefetch of tile s+1 (in flight during compute)
            const int k = ks0 + (s + 1) * 32 + akq;
            if (aval) {
                const float* src = (mode == 1) ? ((k < 512) ? (grow + k) : (drow + (k - 512)))
                                               : (drow + k);
                const float4 x = ((const float4*)src)[0];
                const float4 y = ((const float4*)src)[1];
                av[0]=x.x; av[1]=x.y; av[2]=x.z; av[3]=x.w;
                av[4]=y.x; av[5]=y.y; av[6]=y.z; av[7]=y.w;
            }
            const float* bsrc = B + (size_t)(ks0 + (s + 1) * 32 + brow) * 512 + c0 + bcq;
            const float4 x = ((const float4*)bsrc)[0];
            const float4 y = ((const float4*)bsrc)[1];
            bv[0]=x.x; bv[1]=x.y; bv[2]=x.z; bv[3]=x.w;
            bv[4]=y.x; bv[5]=y.y; bv[6]=y.z; bv[7]=y.w;
        }
        #pragma unroll
        for (int kk = 0; kk < 32; ++kk) {
            const float4 a = *(const float4*)&As[p][kk * LSTR + tm * 4];
            const float4 b = *(const float4*)&Bs[p][kk * LSTR + tn * 4];
            const float ar[4] = {a.x, a.y, a.z, a.w};
            const float br[4] = {b.x, b.y, b.z, b.w};
            #pragma unroll
            for (int i = 0; i < 4; ++i)
                #pragma unroll
                for (int j = 0; j < 4; ++j)
                    acc[i][j] = fmaf(ar[i], br[j], acc[i][j]);
        }
        __syncthreads();
        if (more) {
            const int q2 = p ^ 1;
            #pragma unroll
            for (int i = 0; i < 8; ++i) As[q2][(akq + i) * LSTR + arow] = av[i];
            *(float4*)&Bs[q2][brow * LSTR + bcq]     = make_float4(bv[0], bv[1], bv[2], bv[3]);
            *(float4*)&Bs[q2][brow * LSTR + bcq + 4] = make_float4(bv[4], bv[5], bv[6], bv[7]);
            __syncthreads();
            p = q2;
        }
    }

    // ---- epilogue: write this chunk's partial ----
    float* __restrict__ Cp = C + (size_t)blockIdx.z * MN;
    #pragma unroll
    for (int i = 0; i < 4; ++i) {
        const int r = r0 + tm * 4 + i;
        if (r < M)
            *(float4*)&Cp[(size_t)r * 512 + c0 + tn * 4] =
                make_float4(acc[i][0], acc[i][1], acc[i][2], acc[i][3]);
    }
}

// one block per drug n: scores = (q[n] . rela[adj_rel[n,k]]) / sqrt(512),
// softmax over k, agg[n] = sum_k attn_k * ent[adj_tail[n,k]]
// q arrives as skq split-K partials (summed on load).
__global__ __launch_bounds__(256) void attn_kernel(
    const float* __restrict__ relaW, const float* __restrict__ entW,
    const int* __restrict__ adj_tail, const int* __restrict__ adj_rel,
    const float* __restrict__ q, int skq, float* __restrict__ agg)
{
    const int n = blockIdx.x;
    const int t = threadIdx.x;
    const int lane = t & 63;
    const int w = t >> 6;
    __shared__ float sc[64];
    __shared__ int tails[64];
    __shared__ int rels[64];
    if (t < 64) { tails[t] = adj_tail[n * 64 + t]; rels[t] = adj_rel[n * 64 + t]; }

    float qv[8];
    {
        const float* qp = q + (size_t)n * 512 + lane * 8;
        float4 x = ((const float4*)qp)[0], y = ((const float4*)qp)[1];
        qv[0]=x.x; qv[1]=x.y; qv[2]=x.z; qv[3]=x.w;
        qv[4]=y.x; qv[5]=y.y; qv[6]=y.z; qv[7]=y.w;
        if (skq == 2) {
            const float* qp2 = qp + MN;
            float4 x2 = ((const float4*)qp2)[0], y2 = ((const float4*)qp2)[1];
            qv[0]+=x2.x; qv[1]+=x2.y; qv[2]+=x2.z; qv[3]+=x2.w;
            qv[4]+=y2.x; qv[5]+=y2.y; qv[6]+=y2.z; qv[7]+=y2.w;
        }
    }
    __syncthreads();

    #pragma unroll 4
    for (int kk = 0; kk < 16; ++kk) {
        const int k = w * 16 + kk;
        const float4* p = (const float4*)(relaW + (size_t)rels[k] * 512 + lane * 8);
        float4 x = p[0], y = p[1];
        float s = 0.f;
        s = fmaf(qv[0], x.x, s); s = fmaf(qv[1], x.y, s);
        s = fmaf(qv[2], x.z, s); s = fmaf(qv[3], x.w, s);
        s = fmaf(qv[4], y.x, s); s = fmaf(qv[5], y.y, s);
        s = fmaf(qv[6], y.z, s); s = fmaf(qv[7], y.w, s);
        #pragma unroll
        for (int off = 32; off >= 1; off >>= 1) s += __shfl_xor(s, off, 64);
        if (lane == 0) sc[k] = s * 0.0441941738241592f;  // 1/sqrt(512)
    }
    __syncthreads();

    if (w == 0) {
        float s = sc[lane];
        float m = s;
        #pragma unroll
        for (int off = 32; off >= 1; off >>= 1) m = fmaxf(m, __shfl_xor(m, off, 64));
        const float e = __expf(s - m);
        float sum = e;
        #pragma unroll
        for (int off = 32; off >= 1; off >>= 1) sum += __shfl_xor(sum, off, 64);
        sc[lane] = e / sum;
    }
    __syncthreads();

    float a0 = 0.f, a1 = 0.f;
    const int d2 = t * 2;
    #pragma unroll 8
    for (int k = 0; k < 64; ++k) {
        const float ak = sc[k];
        const float2 u = *(const float2*)(entW + (size_t)tails[k] * 512 + d2);
        a0 = fmaf(ak, u.x, a0);
        a1 = fmaf(ak, u.y, a1);
    }
    ((float2*)(agg + (size_t)n * 512))[t] = make_float2(a0, a1);
}

// Fused (split-K sum + bias + ReLU) + BN + sequential smoothing scan.
// 32 blocks x 16 cols, 512 threads (8 waves). See round-5 notes.
__global__ __launch_bounds__(512) void scan_kernel(
    float* hout, const float* __restrict__ hsrc, int nh,
    const float* __restrict__ linb,
    const float* __restrict__ gamma, const float* __restrict__ beta,
    const int* __restrict__ nbr_idx, const int* __restrict__ nbr_deg,
    const int* __restrict__ epoch)
{
    __shared__ float fs[(N_DRUG + 1) * FS];      // row N_DRUG = zeros (dummy)
    __shared__ int   offs[N_DRUG * MAXDEG];      // padded neighbor rows (dummy=N_DRUG)
    __shared__ float2 ivw[N_DRUG];               // (0.5/deg, 0.5) or (0,1)
    __shared__ int   mxs[N_DRUG];                // max lower-dep row, -1 if none
    __shared__ float part[2][32][16];            // stats partials [s|q][rr][c]
    __shared__ float bnp[2][16];                 // scl, shf per col
    __shared__ int   genext[2];
    __shared__ int   ge0s;

    const int t  = threadIdx.x;
    const int c  = t & 15;
    const int h  = (t >> 4) & 1;
    const int j  = t >> 5;         // node slot 0..15
    const int rr = t >> 4;         // staging row-group 0..31
    const int c0 = blockIdx.x * 16;

    // ---- phase 0a: neighbor table (padded), mx, ivw ----
    for (int i = t; i < N_DRUG; i += 512) {
        const int d = nbr_deg[i];
        ivw[i] = (d > 0) ? make_float2(0.5f / (float)d, 0.5f) : make_float2(0.f, 1.f);
        const int4* np = (const int4*)&nbr_idx[i * MAXDEG];
        int4* op = (int4*)&offs[i * MAXDEG];
        int mx = -1;
        #pragma unroll
        for (int u = 0; u < 8; ++u) {
            int4 qq = np[u];
            const int b = u * 4;
            qq.x = (b + 0 < d) ? qq.x : N_DRUG;
            qq.y = (b + 1 < d) ? qq.y : N_DRUG;
            qq.z = (b + 2 < d) ? qq.z : N_DRUG;
            qq.w = (b + 3 < d) ? qq.w : N_DRUG;
            mx = max(mx, (qq.x < i) ? qq.x : -1);
            mx = max(mx, (qq.y < i) ? qq.y : -1);
            mx = max(mx, (qq.z < i) ? qq.z : -1);
            mx = max(mx, (qq.w < i) ? qq.w : -1);
            op[u] = qq;
        }
        mxs[i] = mx;
    }

    // ---- phase 0b: stage fs = relu(sum partials + bias); partial stats ----
    {
        const float bb = linb[c0 + c];
        float sl = 0.f, ql = 0.f;
        for (int r = rr; r < N_DRUG; r += 32) {
            const float* hp = hsrc + (size_t)r * DIM + c0 + c;
            float v = hp[0];
            for (int pt = 1; pt < nh; ++pt) v += hp[(size_t)pt * MN];
            v = fmaxf(v + bb, 0.f);
            fs[r * FS + c] = v;
            sl += v;
            ql = fmaf(v, v, ql);
        }
        part[0][rr][c] = sl;
        part[1][rr][c] = ql;
    }
    if (t < FS) fs[N_DRUG * FS + t] = 0.f;
    __syncthreads();

    // ---- phase 1: stats finalize (t<16) || first group boundary (wave 7) ----
    if (t < 16) {
        float s = 0.f, sq = 0.f;
        #pragma unroll
        for (int k = 0; k < 32; ++k) { s += part[0][k][t]; sq += part[1][k][t]; }
        const float mean = s * (1.f / N_DRUG);
        const float var = sq * (1.f / N_DRUG) - mean * mean;
        const float rstd = rsqrtf(var + 1e-5f);
        const float scl = gamma[c0 + t] * rstd;
        bnp[0][t] = scl;
        bnp[1][t] = beta[c0 + t] - mean * scl;
    }
    if ((t >> 6) == 7) {
        const int l = t & 63;
        const int jj = 1 + l;
        const bool flag = (l >= 15) || (jj >= N_DRUG) || (mxs[min(jj, N_DRUG - 1)] >= 0);
        const unsigned long long b = __ballot(flag) & 0xFFFFULL;
        if (l == 0) ge0s = 1 + (int)__builtin_ctzll(b);
    }
    __syncthreads();

    // ---- phase 2: BN apply ----
    {
        const float scl = bnp[0][c];
        const float shf = bnp[1][c];
        for (int r = rr; r < N_DRUG; r += 32)
            fs[r * FS + c] = fmaf(fs[r * FS + c], scl, shf);
    }
    __syncthreads();

    // ---- rounds ----
    if (epoch[0] > 1) {
        int gs = 0, ge = ge0s;
        int4 o0, o1, o2, o3;
        {
            const int4* p = (const int4*)&offs[min(j, N_DRUG - 1) * MAXDEG + h * 16];
            o0 = p[0]; o1 = p[1]; o2 = p[2]; o3 = p[3];
        }
        int par = 0;
        while (gs < N_DRUG) {
            const bool pred = (gs + j) < ge;
            float s0 = 0.f, s1 = 0.f, s2 = 0.f, s3 = 0.f;
#define GATH4(Q) { s0 += fs[Q.x * FS + c]; s1 += fs[Q.y * FS + c]; \
                   s2 += fs[Q.z * FS + c]; s3 += fs[Q.w * FS + c]; }
            if (pred) { GATH4(o0) GATH4(o1) GATH4(o2) GATH4(o3) }
#undef GATH4
            int4 n0, n1, n2, n3;
            {
                const int4* p = (const int4*)&offs[min(ge + j, N_DRUG - 1) * MAXDEG + h * 16];
                n0 = p[0]; n1 = p[1]; n2 = p[2]; n3 = p[3];
            }
            float nv = 0.f;
            if (pred) {
                const float cur = fs[(gs + j) * FS + c];
                const float2 iw = ivw[gs + j];
                float sh = (s0 + s1) + (s2 + s3);
                sh += __shfl_xor(sh, 16, 64);    // combine the two halves
                nv = fmaf(sh, iw.x, cur * iw.y);
            }
            if ((t >> 6) == 7) {
                const int l = t & 63;
                const int jj = ge + 1 + l;
                const bool flag = (l >= 15) || (jj >= N_DRUG) ||
                                  (mxs[min(jj, N_DRUG - 1)] >= ge);
                const unsigned long long b = __ballot(flag) & 0xFFFFULL;
                if (l == 0) genext[par] = ge + 1 + (int)__builtin_ctzll(b);
            }
            __syncthreads();   // all reads done before any write (anti-deps)
            if (pred && h == 0) fs[(gs + j) * FS + c] = nv;
            __syncthreads();   // writes + genext visible
            gs = ge;
            ge = genext[par];
            par ^= 1;
            o0 = n0; o1 = n1; o2 = n2; o3 = n3;
        }
    }
    __syncthreads();

    // ---- write back ----
    for (int r = rr; r < N_DRUG; r += 32)
        hout[(size_t)r * DIM + c0 + c] = fs[r * FS + c];
}

extern "C" void kernel_launch(void* const* d_in, const int* in_sizes, int n_in,
                              void* d_out, int out_size, void* d_ws, size_t ws_size,
                              hipStream_t stream)
{
    const float* drugW = (const float*)d_in[0];
    const float* relaW = (const float*)d_in[1];
    const float* entW  = (const float*)d_in[2];
    const float* Wa    = (const float*)d_in[3];
    const float* linW  = (const float*)d_in[4];
    const float* linb  = (const float*)d_in[5];
    const float* gamma = (const float*)d_in[6];
    const float* beta  = (const float*)d_in[7];
    const int* drug_name = (const int*)d_in[8];
    const int* adj_tail  = (const int*)d_in[9];
    const int* adj_rel   = (const int*)d_in[10];
    const int* nbr_idx   = (const int*)d_in[11];
    const int* nbr_deg   = (const int*)d_in[12];
    const int* epoch     = (const int*)d_in[13];

    float* ws = (float*)d_ws;
    float* out = (float*)d_out;

    // big path: q 2 partials + agg + h 4 partials = 7*MN floats (~8.2 MB)
    const bool big = ws_size >= (size_t)7 * MN * sizeof(float);
    const int skq = big ? 2 : 1;
    const int skh = big ? 4 : 1;
    float* q   = ws;
    float* agg = ws + (size_t)(big ? 2 : 1) * MN;
    float* hp  = big ? (ws + (size_t)3 * MN) : out;

    gemm_kernel<<<dim3(8, 9, skq), 256, 0, stream>>>(
        drugW, drug_name, nullptr, Wa, q, N_DRUG, 512 / skq, 0);
    attn_kernel<<<N_DRUG, 256, 0, stream>>>(
        relaW, entW, adj_tail, adj_rel, q, skq, agg);
    gemm_kernel<<<dim3(8, 9, skh), 256, 0, stream>>>(
        drugW, drug_name, agg, linW, hp, N_DRUG, 1024 / skh, 1);
    scan_kernel<<<32, 512, 0, stream>>>(
        out, hp, skh, linb, gamma, beta, nbr_idx, nbr_deg, epoch);
}